// Round 8
// baseline (169.756 us; speedup 1.0000x reference)
//
#include <hip/hip_runtime.h>
#include <math.h>

// MoE top-2-of-8: B=1024, I=512, H=2048, O=512, E=8, K=2.
// R16: read-W-once, fragment-linear gll16 GEMMs.
//  - prep (fused gating): streams W1/W2 fp32 -> bf16 written in the EXACT
//    1KB-subtile lane order the GEMMs' global_load_lds consumes (16n x 32k
//    per subtile, elem (lane&15)=row, (lane>>4)*8=k-oct). Reads contiguous
//    256B row segments, writes 1KB/wave contiguous. Blocks 0..255 also gate.
//  - fc1: block=(e=bid&7, nx 0..31): stage 64n x 512k W1T panel ONCE (64
//    subtiles, 8 gll16/wave -- R13's 2x-overissue bug fixed), ballot-scan
//    slot list overlaps; loop mb over 64-row A tiles (gll16 gather from xb),
//    2 barriers/tile. W1 read exactly once from HBM (16 MB bf16).
//  - fc2: block=(e, nx 0..15, kc 0..1): stage 32n x 1024k W2T half-panel
//    once; per mb 2 k-chunks of A (64m x 512k) -> y2 f32 partials.
//  - 1 blk/CU (132 KB LDS), 8 waves; latency hidden by 8 back-to-back
//    gll16 per wave (~8KB/wave in flight during stages).
//  - combine: kc=2 partial sum, unchanged.
// NOTE: dur_us includes ~81us of harness 256MB poison fills (2 x 40.5us).

#define B_TOK 1024
#define I_DIM 512
#define H_DIM 2048
#define O_DIM 512
#define E_NUM 8
#define CAP   1024                       // per-expert slot capacity

#define WS_COUNTS   0                    // 8 ints (written by fc1 nx==0)
#define WS_TOK_E    64                   // [1024][2] int
#define WS_TOK_W    8256                 // [1024][2] float
#define WS_TOK_SLOT 16448                // [1024][2] int
#define WS_XB       65536                // [1024][512] bf16 = 1 MB
#define WS_W1T      1114112              // [8][32nx][64s][512] bf16 = 16 MB
#define WS_W2T      17891328             // [8][2kc][16nx][64s][512] bf16 = 16 MB
#define WS_HB       34668544             // [8*1024][2048] bf16 = 32 MB
#define WS_Y2       68222976             // [2][8192][512] f32 = 32 MB

typedef __attribute__((ext_vector_type(8))) __bf16 bf16x8;
typedef __attribute__((ext_vector_type(4))) __bf16 bf16x4;
typedef __attribute__((ext_vector_type(2))) __bf16 bf16x2;
typedef __attribute__((ext_vector_type(4))) float f32x4;

#define MFMA16 __builtin_amdgcn_mfma_f32_16x16x32_bf16

// async global->LDS, 16B/lane; LDS dest wave-uniform base (+lane*16 by HW),
// global src per-lane.
__device__ __forceinline__ void gll16(const __bf16* g, __bf16* l)
{
    __builtin_amdgcn_global_load_lds(
        (const __attribute__((address_space(1))) uint32_t*)g,
        (__attribute__((address_space(3))) uint32_t*)(uintptr_t)(void*)l,
        16, 0, 0);
}

// ---------------------------------------------------------------------------
// prep: blocks 0..255 gate 4 tokens (one/wave) + x->xb bf16. ALL 1024 blocks
// then convert one 64k x 256n W tile into fragment-linear bf16 subtiles.
__global__ __launch_bounds__(256) void prep_kernel(
    const float* __restrict__ x, const float* __restrict__ Wg,
    const float* __restrict__ bg, const float* __restrict__ W1f,
    const float* __restrict__ W2f,
    __bf16* __restrict__ xb, int* __restrict__ tok_e,
    float* __restrict__ tok_w,
    __bf16* __restrict__ W1T, __bf16* __restrict__ W2T)
{
    const int tid = threadIdx.x, lane = tid & 63, w = tid >> 6;
    const int l15 = lane & 15, q = lane >> 4;
    const int b = blockIdx.x;

    // ---- gating (blocks 0..255, one token per wave) ----
    if (b < 256) {
        const int t = b * 4 + w;
        const float4* x4 = (const float4*)(x + (size_t)t * I_DIM);
        float4 va = x4[lane], vb = x4[lane + 64];
        bf16x4 oa, ob;
        oa[0] = (__bf16)va.x; oa[1] = (__bf16)va.y;
        oa[2] = (__bf16)va.z; oa[3] = (__bf16)va.w;
        ob[0] = (__bf16)vb.x; ob[1] = (__bf16)vb.y;
        ob[2] = (__bf16)vb.z; ob[3] = (__bf16)vb.w;
        *(bf16x4*)(xb + (size_t)t * I_DIM + lane * 4) = oa;
        *(bf16x4*)(xb + (size_t)t * I_DIM + 256 + lane * 4) = ob;

        float gacc[8];
#pragma unroll
        for (int e = 0; e < 8; ++e) gacc[e] = 0.f;
        float xv[8] = {va.x, va.y, va.z, va.w, vb.x, vb.y, vb.z, vb.w};
#pragma unroll
        for (int u = 0; u < 8; ++u) {
            int i = (u < 4) ? (lane * 4 + u) : (256 + lane * 4 + u - 4);
            const float4* wr = (const float4*)(Wg + (size_t)i * 8);
            float4 wa = wr[0], wb2 = wr[1];
            gacc[0] = fmaf(xv[u], wa.x, gacc[0]);
            gacc[1] = fmaf(xv[u], wa.y, gacc[1]);
            gacc[2] = fmaf(xv[u], wa.z, gacc[2]);
            gacc[3] = fmaf(xv[u], wa.w, gacc[3]);
            gacc[4] = fmaf(xv[u], wb2.x, gacc[4]);
            gacc[5] = fmaf(xv[u], wb2.y, gacc[5]);
            gacc[6] = fmaf(xv[u], wb2.z, gacc[6]);
            gacc[7] = fmaf(xv[u], wb2.w, gacc[7]);
        }
#pragma unroll
        for (int off = 32; off > 0; off >>= 1)
#pragma unroll
            for (int e = 0; e < 8; ++e)
                gacc[e] += __shfl_xor(gacc[e], off, 64);
        if (lane == 0) {
            float l[8];
#pragma unroll
            for (int e = 0; e < 8; ++e) l[e] = gacc[e] + bg[e];
            int E0 = 0;
            for (int e = 1; e < 8; ++e) if (l[e] > l[E0]) E0 = e;
            int E1 = (E0 == 0) ? 1 : 0;
            for (int e = 0; e < 8; ++e) {
                if (e == E0) continue;
                if (l[e] > l[E1]) E1 = e;
            }
            float w0 = 1.f / (1.f + expf(l[E1] - l[E0]));  // p0/(p0+p1)
            tok_e[t * 2]     = E0;
            tok_e[t * 2 + 1] = E1;
            tok_w[t * 2]     = w0;
            tok_w[t * 2 + 1] = 1.f - w0;
        }
    }

    // ---- tile select ----
    const float* src; int NWs, k0, n0, e, t;
    const bool isW1 = (b < 512);
    if (isW1) {
        e = b >> 6; t = b & 63;
        src = W1f + (size_t)e * I_DIM * H_DIM;
        NWs = H_DIM; k0 = (t >> 3) * 64; n0 = (t & 7) * 256;
    } else {
        const int u = b - 512; e = u >> 6; t = u & 63;
        src = W2f + (size_t)e * H_DIM * O_DIM;
        NWs = O_DIM; k0 = (t >> 1) * 64; n0 = (t & 1) * 256;
    }

    __shared__ uint32_t T[256 * 33];     // [n][k-pair] packed bf16x2, 33 KB
#pragma unroll
    for (int i = 0; i < 8; ++i) {        // 2048 read units / 256 thr
        const int u = tid + 256 * i;
        const int p = u >> 6, c4 = u & 63;      // k-pair, n-quad
        const float* wp = src + (size_t)(k0 + 2 * p) * NWs + n0 + c4 * 4;
        float4 r0 = *(const float4*)wp;
        float4 r1 = *(const float4*)(wp + NWs);
        const float* f0 = (const float*)&r0;
        const float* f1 = (const float*)&r1;
#pragma unroll
        for (int j = 0; j < 4; ++j) {
            bf16x2 pk;
            pk[0] = (__bf16)f0[j];
            pk[1] = (__bf16)f1[j];
            *(bf16x2*)&T[(c4 * 4 + j) * 33 + p] = pk;
        }
    }
    __syncthreads();

    // ---- write 32 fragment-linear subtiles (1KB each), 1KB/wave coalesced.
#pragma unroll
    for (int i = 0; i < 8; ++i) {
        const int sidx = w + 4 * i;              // 0..31
        if (isW1) {
            const int p4 = sidx >> 3, jj = (sidx >> 1) & 3, kk = sidx & 1;
            const int nn = p4 * 64 + jj * 16 + l15;
            const int kp = kk * 16 + q * 4;
            uint4 d;
            d.x = T[nn * 33 + kp + 0];
            d.y = T[nn * 33 + kp + 1];
            d.z = T[nn * 33 + kp + 2];
            d.w = T[nn * 33 + kp + 3];
            const int nxg = (t & 7) * 4 + p4;
            const int ksg = (t >> 3) * 2 + kk;
            const int s = jj * 16 + ksg;
            *(uint4*)(W1T + (size_t)e * 1048576 + (size_t)nxg * 32768
                      + s * 512 + lane * 8) = d;
        } else {
            const int p8 = sidx >> 2, jj = (sidx >> 1) & 1, kk = sidx & 1;
            const int nn = p8 * 32 + jj * 16 + l15;
            const int kp = kk * 16 + q * 4;
            uint4 d;
            d.x = T[nn * 33 + kp + 0];
            d.y = T[nn * 33 + kp + 1];
            d.z = T[nn * 33 + kp + 2];
            d.w = T[nn * 33 + kp + 3];
            const int kc = k0 >> 10;
            const int ksh = ((k0 & 1023) >> 5) + kk;
            const int nxg = (t & 1) * 8 + p8;
            const int s = jj * 32 + ksh;
            *(uint4*)(W2T + (size_t)e * 1048576 + (size_t)kc * 524288
                      + (size_t)nxg * 32768 + s * 512 + lane * 8) = d;
        }
    }
}

// ---------------------------------------------------------------------------
// fc1: 256 blocks x 512 thr. block=(e=bid&7, nx=bid>>3). B panel (64 KB)
// staged once; A 64-row tiles gathered per mb. hb out (+bias, relu).
__global__ __launch_bounds__(512, 2) void fc1_kernel(
    const __bf16* __restrict__ xb, const __bf16* __restrict__ W1T,
    const float* __restrict__ b1, const int* __restrict__ tok_e,
    int* __restrict__ counts, int* __restrict__ tok_slot,
    __bf16* __restrict__ hb)
{
    const int tid = threadIdx.x, lane = tid & 63, w = tid >> 6;
    const int l15 = lane & 15, q = lane >> 4;
    const int wm = w >> 1, wn = w & 1;
    const int e = blockIdx.x & 7, nx = blockIdx.x >> 3;
    const int n0 = nx * 64, off = e * CAP;

    __shared__ __align__(16) __bf16 Bs[64 * 512];   // 64 KB
    __shared__ __align__(16) __bf16 As[64 * 512];   // 64 KB
    __shared__ int sl[CAP];
    __shared__ int sMe;

    // ---- issue B staging: 64 subtiles, 8 gll16 per wave (exact count).
    const __bf16* WB = W1T + (size_t)e * 1048576 + (size_t)nx * 32768;
#pragma unroll
    for (int i = 0; i < 8; ++i) {
        const int s = w * 8 + i;
        gll16(WB + s * 512 + lane * 8, Bs + s * 512);
    }

    // ---- wave-0 ballot scan (overlaps B staging).
    if (w == 0) {
        int cnt = 0;
#pragma unroll
        for (int bb = 0; bb < 2; ++bb) {
            int vals[16];
#pragma unroll
            for (int c = 0; c < 16; ++c)
                vals[c] = tok_e[(bb * 16 + c) * 64 + lane];
#pragma unroll
            for (int c = 0; c < 16; ++c) {
                const int gidx = (bb * 16 + c) * 64 + lane;
                const bool hit = (vals[c] == e);
                const unsigned long long mk = __ballot(hit);
                if (hit) {
                    const int pos = cnt + __popcll(mk & ((1ull << lane) - 1));
                    sl[pos] = gidx >> 1;
                    if (nx == 0) tok_slot[gidx] = off + pos;
                }
                cnt += __popcll(mk);
            }
        }
        if (lane == 0) {
            sMe = cnt;
            if (nx == 0) counts[e] = cnt;
        }
    }
    __syncthreads();                     // B + slot list resident
    const int Me = sMe;

    for (int mb = 0; mb < Me; mb += 64) {
        // ---- stage A tile: 64 subtiles (16m x 32k), gathered rows.
#pragma unroll
        for (int i = 0; i < 8; ++i) {
            const int s = w * 8 + i;
            const int msub = s >> 4, ks = s & 15;
            int r = mb + msub * 16 + l15; if (r >= Me) r = Me - 1;
            gll16(xb + (size_t)sl[r] * I_DIM + ks * 32 + q * 8, As + s * 512);
        }
        __syncthreads();                 // A resident

        f32x4 acc[2] = {};
#pragma unroll
        for (int ks = 0; ks < 16; ++ks) {
            bf16x8 a = *(const bf16x8*)&As[(wm * 16 + ks) * 512 + lane * 8];
            bf16x8 b0 = *(const bf16x8*)&Bs[((wn * 2 + 0) * 16 + ks) * 512 + lane * 8];
            bf16x8 b1 = *(const bf16x8*)&Bs[((wn * 2 + 1) * 16 + ks) * 512 + lane * 8];
            acc[0] = MFMA16(a, b0, acc[0], 0, 0, 0);
            acc[1] = MFMA16(a, b1, acc[1], 0, 0, 0);
        }
        // epilogue: C/D layout col=l15, row=q*4+r (verified m89)
#pragma unroll
        for (int jj = 0; jj < 2; ++jj) {
            const int gn = n0 + (wn * 2 + jj) * 16 + l15;
            const float bv = b1[e * H_DIM + gn];
#pragma unroll
            for (int r = 0; r < 4; ++r) {
                const int m = mb + wm * 16 + q * 4 + r;
                if (m < Me) {
                    float v = acc[jj][r] + bv;
                    hb[(size_t)(off + m) * H_DIM + gn] = (__bf16)fmaxf(v, 0.f);
                }
            }
        }
        __syncthreads();                 // readers done before next A stage
    }
}

// ---------------------------------------------------------------------------
// fc2: 256 blocks x 512 thr. block=(e=bid&7, nx=(bid>>3)&15, kc=bid>>7).
// B half-panel (32n x 1024k) staged once; per mb 2 A k-chunks -> y2 partials.
__global__ __launch_bounds__(512, 2) void fc2_kernel(
    const __bf16* __restrict__ hb, const __bf16* __restrict__ W2T,
    const int* __restrict__ counts, float* __restrict__ y2)
{
    const int tid = threadIdx.x, lane = tid & 63, w = tid >> 6;
    const int l15 = lane & 15, q = lane >> 4;
    const int wm = w >> 1, wn = w & 1;
    const int e = blockIdx.x & 7;
    const int nx = (blockIdx.x >> 3) & 15, kc = blockIdx.x >> 7;
    const int n0 = nx * 32, off = e * CAP;
    const int Me = counts[e];
    if (Me == 0) return;

    __shared__ __align__(16) __bf16 Bs[64 * 512];   // 64 KB
    __shared__ __align__(16) __bf16 As[64 * 512];   // 64 KB

    const __bf16* WB = W2T + (size_t)e * 1048576 + (size_t)kc * 524288
                       + (size_t)nx * 32768;
#pragma unroll
    for (int i = 0; i < 8; ++i) {
        const int s = w * 8 + i;
        gll16(WB + s * 512 + lane * 8, Bs + s * 512);
    }
    __syncthreads();                     // B resident

    for (int mb = 0; mb < Me; mb += 64) {
        f32x4 acc = {};
#pragma unroll
        for (int kch = 0; kch < 2; ++kch) {
            // stage A chunk: 64 subtiles (16m x 32k)
#pragma unroll
            for (int i = 0; i < 8; ++i) {
                const int s = w * 8 + i;
                const int msub = s >> 4, ks = s & 15;
                int r = mb + msub * 16 + l15; if (r >= Me) r = Me - 1;
                gll16(hb + (size_t)(off + r) * H_DIM + kc * 1024 + kch * 512
                      + ks * 32 + q * 8, As + s * 512);
            }
            __syncthreads();             // A chunk resident
#pragma unroll
            for (int ks = 0; ks < 16; ++ks) {
                bf16x8 a = *(const bf16x8*)&As[(wm * 16 + ks) * 512 + lane * 8];
                bf16x8 b = *(const bf16x8*)
                    &Bs[(wn * 32 + kch * 16 + ks) * 512 + lane * 8];
                acc = MFMA16(a, b, acc, 0, 0, 0);
            }
            __syncthreads();             // readers done before next stage
        }
        // epilogue
        const int gn = n0 + wn * 16 + l15;
#pragma unroll
        for (int r = 0; r < 4; ++r) {
            const int m = mb + wm * 16 + q * 4 + r;
            if (m < Me)
                y2[((size_t)kc * (E_NUM * CAP) + off + m) * O_DIM + gn] = acc[r];
        }
    }
}

// ---------------------------------------------------------------------------
// out[t][c] = sum_k w_k * (b2[e_k][c] + sum_kc y2[kc][slot_k][c])
__global__ __launch_bounds__(256) void combine_kernel(
    const float* __restrict__ y2, const float* __restrict__ b2,
    const int* __restrict__ tok_slot, const int* __restrict__ tok_e,
    const float* __restrict__ tok_w, float* __restrict__ out)
{
    const int idx = blockIdx.x * 256 + threadIdx.x;   // B*O/4
    const int t = idx >> 7;
    const int c = (idx & 127) * 4;
    float4 sum = {0.f, 0.f, 0.f, 0.f};
#pragma unroll
    for (int k = 0; k < 2; ++k) {
        const int s = tok_slot[t * 2 + k];
        const int e = tok_e[t * 2 + k];
        const float wgt = tok_w[t * 2 + k];
        float4 a = *(const float4*)(b2 + (size_t)e * O_DIM + c);
#pragma unroll
        for (int kc = 0; kc < 2; ++kc) {
            float4 v = *(const float4*)
                (y2 + ((size_t)kc * (E_NUM * CAP) + s) * O_DIM + c);
            a.x += v.x; a.y += v.y; a.z += v.z; a.w += v.w;
        }
        sum.x += wgt * a.x; sum.y += wgt * a.y;
        sum.z += wgt * a.z; sum.w += wgt * a.w;
    }
    *(float4*)(out + (size_t)t * O_DIM + c) = sum;
}

// ===========================================================================
extern "C" void kernel_launch(void* const* d_in, const int* in_sizes, int n_in,
                              void* d_out, int out_size, void* d_ws, size_t ws_size,
                              hipStream_t stream)
{
    const float* x  = (const float*)d_in[0];
    const float* Wg = (const float*)d_in[1];
    const float* bg = (const float*)d_in[2];
    const float* W1 = (const float*)d_in[3];
    const float* b1 = (const float*)d_in[4];
    const float* W2 = (const float*)d_in[5];
    const float* b2 = (const float*)d_in[6];
    float* out = (float*)d_out;
    char* ws = (char*)d_ws;

    int*    counts   = (int*)(ws + WS_COUNTS);
    int*    tok_e    = (int*)(ws + WS_TOK_E);
    float*  tok_w    = (float*)(ws + WS_TOK_W);
    int*    tok_slot = (int*)(ws + WS_TOK_SLOT);
    __bf16* xb       = (__bf16*)(ws + WS_XB);
    __bf16* W1T      = (__bf16*)(ws + WS_W1T);
    __bf16* W2T      = (__bf16*)(ws + WS_W2T);
    __bf16* hb       = (__bf16*)(ws + WS_HB);
    float*  y2       = (float*)(ws + WS_Y2);

    // gating + W -> fragment-linear bf16 (96 MB streamed)
    prep_kernel<<<1024, 256, 0, stream>>>(x, Wg, bg, W1, W2,
                                          xb, tok_e, tok_w, W1T, W2T);
    // fc1: 8e x 32nx = 256 blocks (1/CU, W1 read once)
    fc1_kernel<<<256, 512, 0, stream>>>(
        xb, W1T, b1, tok_e, counts, tok_slot, hb);
    // fc2: 8e x 16nx x 2kc = 256 blocks (1/CU, W2 read once)
    fc2_kernel<<<256, 512, 0, stream>>>(hb, W2T, counts, y2);
    combine_kernel<<<(B_TOK * O_DIM / 4) / 256, 256, 0, stream>>>(
        y2, b2, tok_slot, tok_e, tok_w, out);
}